// Round 3
// baseline (76.834 us; speedup 1.0000x reference)
//
#include <hip/hip_runtime.h>

// Problem constants (match reference)
#define LSEQ 2048   // sequence length
#define NS   1022   // number of distances s = 2..1023
#define NF   5110   // NS * 5 output features
#define NB   8      // batch
#define IT   64     // i-positions per block
#define GI   4      // i-positions per store group
#define NGRP (IT / GI)  // 16 groups
#define TPB  256
#define FPB  (TPB * 5)  // 1280 contiguous features per block

// base pairing score: 2*y0*z3 + 3*y1*z2 + 3*y2*z1 + 2*y3*z0
__device__ __forceinline__ float basescore(const float4 y, const float4 z) {
    return 2.f * y.x * z.w + 3.f * y.y * z.z + 3.f * y.z * z.y + 2.f * y.w * z.x;
}

// clamped load: zero outside [0, LSEQ)
__device__ __forceinline__ float4 loadx(const float4* __restrict__ xg, int p) {
    int pc = p < 0 ? 0 : (p > LSEQ - 1 ? LSEQ - 1 : p);
    float4 v = xg[pc];
    if ((unsigned)p >= (unsigned)LSEQ) v = make_float4(0.f, 0.f, 0.f, 0.f);
    return v;
}

__global__ __launch_bounds__(TPB) void fdcnn_kernel(const float4* __restrict__ x,
                                                    float* __restrict__ out) {
    __shared__ float st[2][GI][FPB];   // 40 KB double-buffered output stage

    const int t = threadIdx.x;
    const int n = blockIdx.z;
    const float4* xg = x + (size_t)n * LSEQ;   // row is 32 KB -> L1-resident

    const int sidx = blockIdx.x * TPB + t;  // 0..1023 (>=NS lanes clipped at store)
    const int s = sidx + 2;
    const int i0 = blockIdx.y * IT;
    const int fbase = blockIdx.x * FPB;

    // Rolling window: at i need y1..y3 = x[i+s+1..3], z1..z3 = x[i-s-1..-3].
    float4 yA = loadx(xg, i0 + s + 1);   // y1
    float4 yB = loadx(xg, i0 + s + 2);   // y2
    float4 zA = loadx(xg, i0 - s - 3);   // z3
    float4 zB = loadx(xg, i0 - s - 2);   // z2

    auto compute_group = [&](int g) {
        float* stg = &st[g & 1][0][0];
        #pragma unroll
        for (int ig = 0; ig < GI; ++ig) {
            const int i = i0 + g * GI + ig;
            float4 yC = loadx(xg, i + s + 3);   // coalesced: consecutive lanes -> consecutive addrs
            float4 zC = loadx(xg, i - s - 1);   // coalesced (descending)
            const float4 y1 = yA, y2 = yB, y3 = yC;
            const float4 z3 = zA, z2 = zB, z1 = zC;
            float* sp = stg + ig * FPB + t * 5;  // stride-5 dwords: 2 lanes/bank = free
            sp[0] = basescore(y1, z1) + 2.f * (y1.z * z1.w + y1.w * z1.z);  // main + GU
            sp[1] = basescore(y1, z2);   // left bulge d=1
            sp[2] = basescore(y1, z3);   // left bulge d=2
            sp[3] = basescore(y2, z1);   // right bulge d=1
            sp[4] = basescore(y3, z1);   // right bulge d=2
            yA = yB; yB = yC;
            zA = zB; zB = zC;
        }
    };

    compute_group(0);

    for (int g = 0; g < NGRP; ++g) {
        // LDS-only barrier: do NOT drain vmcnt -- global stores stay in flight.
        asm volatile("s_waitcnt lgkmcnt(0)\n\ts_barrier" ::: "memory");

        if (g + 1 < NGRP) compute_group(g + 1);   // fills st[(g+1)&1]

        // store group g from st[g&1]: 5 coalesced float4 per thread
        const float* stg = &st[g & 1][0][0];
        float* obase = out + ((size_t)n * LSEQ + (i0 + g * GI)) * (size_t)NF + fbase;
        #pragma unroll
        for (int k = 0; k < 5; ++k) {
            const int v  = k * TPB + t;          // 0..1279 flat float4 index
            const int ig = v / 320;              // 320 float4 per i-row
            const int fo = (v - ig * 320) * 4;   // float offset within block's features
            const int rem = NF - (fbase + fo);
            const float4 val = *(const float4*)(stg + ig * FPB + fo);
            float* dst = obase + (size_t)ig * NF + fo;
            if (rem >= 4) {
                *(float4*)dst = val;
            } else if (rem > 0) {                // feature tail (rem==2)
                dst[0] = val.x;
                if (rem > 1) dst[1] = val.y;
            }
        }
    }
}

extern "C" void kernel_launch(void* const* d_in, const int* in_sizes, int n_in,
                              void* d_out, int out_size, void* d_ws, size_t ws_size,
                              hipStream_t stream) {
    const float4* x = (const float4*)d_in[0];
    float* out = (float*)d_out;
    dim3 grid((NS + TPB - 1) / TPB, LSEQ / IT, NB);  // (4, 32, 8) = 1024 blocks = 4/CU
    dim3 block(TPB);
    fdcnn_kernel<<<grid, block, 0, stream>>>(x, out);
}

// Round 4
// 73.328 us; speedup vs baseline: 1.0478x; 1.0478x over previous
//
#include <hip/hip_runtime.h>

// Problem constants (match reference)
#define LSEQ 2048   // sequence length
#define NS   1022   // number of distances s = 2..1023
#define NF   5110   // NS * 5 output features
#define NB   8      // batch
#define IT   64     // i-positions per block
#define GI   4      // i-positions per store group
#define NGRP (IT / GI)  // 16 groups
#define TPB  256
#define FPB  (TPB * 5)  // 1280 contiguous features per block
#define WLEN 324        // LDS window length (need 321, pad to 324)

// base pairing score: 2*y0*z3 + 3*y1*z2 + 3*y2*z1 + 2*y3*z0
__device__ __forceinline__ float basescore(const float4 y, const float4 z) {
    return 2.f * y.x * z.w + 3.f * y.y * z.z + 3.f * y.z * z.y + 2.f * y.w * z.x;
}

__global__ __launch_bounds__(TPB) void fdcnn_kernel(const float4* __restrict__ x,
                                                    float* __restrict__ out) {
    // ys[j] = x[i0 + sx + 1 + j]       (y_d for (ii,t,d) at j = ii + t + d-1)
    // zs[j] = x[i0 - sx - 258 + j]     (z_d for (ii,t,d) at j = ii - t - d + 258)
    __shared__ float4 ys[WLEN];
    __shared__ float4 zs[WLEN];
    __shared__ float st[2][GI][FPB];   // 40 KB double-buffered output stage

    const int t = threadIdx.x;
    const int n = blockIdx.z;
    const int bx = blockIdx.x;
    const int i0 = blockIdx.y * IT;
    const int sx = bx * TPB + 2;                    // s of lane 0
    const float4* xg = x + (size_t)n * LSEQ;
    const int fbase = bx * FPB;

    // ---- one-time window fill (the ONLY global loads; drained once below) ----
    for (int j = t; j < WLEN; j += TPB) {
        int py = i0 + sx + 1 + j;                   // >= 3 always
        float4 vy = xg[py > LSEQ - 1 ? LSEQ - 1 : py];
        if (py >= LSEQ) vy = make_float4(0.f, 0.f, 0.f, 0.f);
        ys[j] = vy;
        int pz = i0 - sx - 258 + j;                 // <= 2047 always
        float4 vz = xg[pz < 0 ? 0 : pz];
        if (pz < 0) vz = make_float4(0.f, 0.f, 0.f, 0.f);
        zs[j] = vz;
    }
    __syncthreads();   // full drain OK here: before any output stores exist

    // rolling registers: y1=ys[ii+t], y2=ys[ii+t+1], y3=ys[ii+t+2]
    //                    z1=zs[ii+257-t], z2=zs[ii+256-t], z3=zs[ii+255-t]
    float4 yA = ys[t];          // y1 @ ii=0
    float4 yB = ys[t + 1];      // y2 @ ii=0
    float4 zA = zs[255 - t];    // z3 @ ii=0
    float4 zB = zs[256 - t];    // z2 @ ii=0

    auto compute_group = [&](int g) {
        float* stg = &st[g & 1][0][0];
        #pragma unroll
        for (int ig = 0; ig < GI; ++ig) {
            const int ii = g * GI + ig;
            float4 yC = ys[ii + t + 2];        // new y3
            float4 zC = zs[ii + 257 - t];      // new z1
            const float4 y1 = yA, y2 = yB, y3 = yC;
            const float4 z3 = zA, z2 = zB, z1 = zC;
            float* sp = stg + ig * FPB + t * 5;   // stride-5 dwords: 2 lanes/bank = free
            sp[0] = basescore(y1, z1) + 2.f * (y1.z * z1.w + y1.w * z1.z);  // main + GU
            sp[1] = basescore(y1, z2);   // left bulge d=1
            sp[2] = basescore(y1, z3);   // left bulge d=2
            sp[3] = basescore(y2, z1);   // right bulge d=1
            sp[4] = basescore(y3, z1);   // right bulge d=2
            yA = yB; yB = yC;
            zA = zB; zB = zC;
        }
    };

    compute_group(0);

    for (int g = 0; g < NGRP; ++g) {
        // LDS-only barrier: never drains vmcnt -- output stores stay in flight.
        asm volatile("s_waitcnt lgkmcnt(0)\n\ts_barrier" ::: "memory");

        if (g + 1 < NGRP) compute_group(g + 1);   // fills st[(g+1)&1]

        // store group g from st[g&1]: 5 coalesced float4 per thread, fire-and-forget
        const float* stg = &st[g & 1][0][0];
        float* obase = out + ((size_t)n * LSEQ + (i0 + g * GI)) * (size_t)NF + fbase;
        #pragma unroll
        for (int k = 0; k < 5; ++k) {
            const int v  = k * TPB + t;          // 0..1279 flat float4 index
            const int ig = v / 320;              // 320 float4 per i-row
            const int fo = (v - ig * 320) * 4;   // float offset within block's features
            const int rem = NF - (fbase + fo);
            const float4 val = *(const float4*)(stg + ig * FPB + fo);
            float* dst = obase + (size_t)ig * NF + fo;
            if (rem >= 4) {
                *(float4*)dst = val;
            } else if (rem > 0) {                // feature tail (rem==2)
                dst[0] = val.x;
                if (rem > 1) dst[1] = val.y;
            }
        }
    }
}

extern "C" void kernel_launch(void* const* d_in, const int* in_sizes, int n_in,
                              void* d_out, int out_size, void* d_ws, size_t ws_size,
                              hipStream_t stream) {
    const float4* x = (const float4*)d_in[0];
    float* out = (float*)d_out;
    dim3 grid((NS + TPB - 1) / TPB, LSEQ / IT, NB);  // (4, 32, 8) = 1024 blocks
    dim3 block(TPB);
    fdcnn_kernel<<<grid, block, 0, stream>>>(x, out);
}